// Round 4
// baseline (807.617 us; speedup 1.0000x reference)
//
#include <hip/hip_runtime.h>

// ---------------------------------------------------------------------------
// GCN, bf16 pipeline. Aggregation = CSR gather (HBM-bound, ~structural limit).
// GEMMs: B-in-registers MFMA, no LDS, no barriers (K<=256, N<=256 makes a
// 64-col B panel x full K fit in 128 VGPRs/lane). A frags straight from
// global (wave pattern = 16 rows x 64B contiguous -> fully dense lines).
// ---------------------------------------------------------------------------

typedef __attribute__((ext_vector_type(8))) short bf16x8;
typedef __attribute__((ext_vector_type(4))) float f32x4;

__device__ __forceinline__ float bf_lo(unsigned u) {
    union { unsigned i; float f; } x; x.i = u << 16; return x.f;
}
__device__ __forceinline__ float bf_hi(unsigned u) {
    union { unsigned i; float f; } x; x.i = u & 0xFFFF0000u; return x.f;
}
__device__ __forceinline__ unsigned short f2bf(float f) {  // RNE
    union { float f; unsigned i; } x; x.f = f;
    unsigned r = x.i + 0x7FFFu + ((x.i >> 16) & 1u);
    return (unsigned short)(r >> 16);
}

// ----------------------------- CSR build -----------------------------------

__global__ __launch_bounds__(256) void count_edges(const int* __restrict__ col,
                                                   int E, int* __restrict__ cnt) {
    int e = blockIdx.x * 256 + threadIdx.x;
    if (e < E) atomicAdd(&cnt[col[e]], 1);
}

__global__ __launch_bounds__(256) void scan_reduce(const int* __restrict__ cnt, int Nn,
                                                   int* __restrict__ blockSums) {
    __shared__ int s[256];
    int t = threadIdx.x;
    int base = blockIdx.x * 2048 + t * 8;
    int v = 0;
#pragma unroll
    for (int j = 0; j < 8; ++j) {
        int i = base + j;
        if (i < Nn) v += cnt[i];
    }
    s[t] = v;
    __syncthreads();
    for (int off = 128; off > 0; off >>= 1) {
        if (t < off) s[t] += s[t + off];
        __syncthreads();
    }
    if (t == 0) blockSums[blockIdx.x] = s[0];
}

// scan_finish also folds in the cross-block prefix (nb <= ~49: serial sum in
// thread 0 is L2-hot and trivial) -> scan_partials kernel eliminated.
__global__ __launch_bounds__(256) void scan_finish(const int* __restrict__ cnt, int Nn,
                                                   const int* __restrict__ blockSums, int nb,
                                                   int* __restrict__ offs,
                                                   int* __restrict__ cursor,
                                                   float* __restrict__ dinv) {
    __shared__ int s[256];
    __shared__ int basePrefix;
    int t = threadIdx.x;
    if (t == 0) {
        int p = 0;
        for (int i = 0; i < (int)blockIdx.x; ++i) p += blockSums[i];
        basePrefix = p;
    }
    int base = blockIdx.x * 2048 + t * 8;
    int c[8];
    int sum = 0;
#pragma unroll
    for (int j = 0; j < 8; ++j) {
        int i = base + j;
        c[j] = (i < Nn) ? cnt[i] : 0;
        sum += c[j];
    }
    s[t] = sum;
    __syncthreads();
    for (int off = 1; off < 256; off <<= 1) {
        int v = (t >= off) ? s[t - off] : 0;
        __syncthreads();
        s[t] += v;
        __syncthreads();
    }
    int run = ((t > 0) ? s[t - 1] : 0) + basePrefix;
#pragma unroll
    for (int j = 0; j < 8; ++j) {
        int i = base + j;
        if (i < Nn) {
            offs[i] = run;
            cursor[i] = run;
            dinv[i] = rsqrtf((float)(c[j] + 1));  // +1 self loop
            run += c[j];
        }
    }
    if (blockIdx.x == (unsigned)(nb - 1) && t == 255) offs[Nn] = basePrefix + s[255];
}

__global__ __launch_bounds__(256) void fill_csr(const int* __restrict__ row,
                                                const int* __restrict__ col, int E,
                                                int* __restrict__ cursor,
                                                int* __restrict__ esrc) {
    int e = blockIdx.x * 256 + threadIdx.x;
    if (e < E) {
        int pos = atomicAdd(&cursor[col[e]], 1);
        esrc[pos] = row[e];
    }
}

// --------------------- fused converts (x + 3 weights) -----------------------

__global__ __launch_bounds__(256) void conv_fused(const float4* __restrict__ x4,
                                                  uint2* __restrict__ xb, int n4,
                                                  const float* __restrict__ W0,
                                                  const float* __restrict__ W1,
                                                  const float* __restrict__ W2,
                                                  unsigned short* __restrict__ Wt0,
                                                  unsigned short* __restrict__ Wt1,
                                                  unsigned short* __restrict__ Wt2) {
    int i = blockIdx.x * 256 + threadIdx.x;
    if (i < n4) {
        float4 v = x4[i];
        uint2 o;
        o.x = (unsigned)f2bf(v.x) | ((unsigned)f2bf(v.y) << 16);
        o.y = (unsigned)f2bf(v.z) | ((unsigned)f2bf(v.w) << 16);
        xb[i] = o;
        return;
    }
    int j = i - n4;
    if (j < 32768) {                       // Wt0[n*128+k] = W0[k*256+n]
        int n = j >> 7, k = j & 127;
        Wt0[j] = f2bf(W0[(size_t)k * 256 + n]);
    } else if (j < 32768 + 65536) {        // Wt1[n*256+k] = W1[k*256+n]
        int q = j - 32768;
        int n = q >> 8, k = q & 255;
        Wt1[q] = f2bf(W1[(size_t)k * 256 + n]);
    } else if (j < 32768 + 65536 + 32768) {// Wt2[n*256+k] = W2[k*128+n]
        int q = j - 98304;
        int n = q >> 8, k = q & 255;
        Wt2[q] = f2bf(W2[(size_t)k * 128 + n]);
    }
}

// ----------------------------- aggregation ---------------------------------
// One wave per dest node. bf16 rows packed 2/uint; UPL uints per lane.
// D = 128*UPL. out[c] = dinv[c]*( dinv[c]*h[c] + sum_s dinv[s]*h[s] ) [+bias]
template<int UPL, bool OUTBF, bool BIAS>
__global__ __launch_bounds__(256) void aggregate_bf(const unsigned* __restrict__ hb,
                                                    const float* __restrict__ dinv,
                                                    const int* __restrict__ offs,
                                                    const int* __restrict__ esrc,
                                                    const float* __restrict__ bias,
                                                    void* __restrict__ out, int Nn) {
    int node = (int)((blockIdx.x * 256u + threadIdx.x) >> 6);
    if (node >= Nn) return;
    int lane = threadIdx.x & 63;
    const int RW = 64 * UPL;  // uints per row
    float dc = dinv[node];
    float acc[2 * UPL];
    {
        const unsigned* p = hb + (size_t)node * RW + lane * UPL;
        unsigned u[UPL];
#pragma unroll
        for (int q = 0; q < UPL; ++q) u[q] = p[q];
#pragma unroll
        for (int q = 0; q < UPL; ++q) {
            acc[2 * q]     = dc * bf_lo(u[q]);
            acc[2 * q + 1] = dc * bf_hi(u[q]);
        }
    }
    int e0 = offs[node], e1 = offs[node + 1];
    int k = e0;
    for (; k + 2 <= e1; k += 2) {
        int s0 = esrc[k], s1 = esrc[k + 1];
        float d0 = dinv[s0], d1 = dinv[s1];
        const unsigned* p0 = hb + (size_t)s0 * RW + lane * UPL;
        const unsigned* p1 = hb + (size_t)s1 * RW + lane * UPL;
        unsigned a0[UPL], a1[UPL];
#pragma unroll
        for (int q = 0; q < UPL; ++q) { a0[q] = p0[q]; a1[q] = p1[q]; }
#pragma unroll
        for (int q = 0; q < UPL; ++q) {
            acc[2 * q]     = fmaf(d0, bf_lo(a0[q]), acc[2 * q]);
            acc[2 * q + 1] = fmaf(d0, bf_hi(a0[q]), acc[2 * q + 1]);
            acc[2 * q]     = fmaf(d1, bf_lo(a1[q]), acc[2 * q]);
            acc[2 * q + 1] = fmaf(d1, bf_hi(a1[q]), acc[2 * q + 1]);
        }
    }
    if (k < e1) {
        int s0 = esrc[k];
        float d0 = dinv[s0];
        const unsigned* p0 = hb + (size_t)s0 * RW + lane * UPL;
#pragma unroll
        for (int q = 0; q < UPL; ++q) {
            unsigned u = p0[q];
            acc[2 * q]     = fmaf(d0, bf_lo(u), acc[2 * q]);
            acc[2 * q + 1] = fmaf(d0, bf_hi(u), acc[2 * q + 1]);
        }
    }
    if (OUTBF) {
        unsigned* o = (unsigned*)out + (size_t)node * RW + lane * UPL;
#pragma unroll
        for (int q = 0; q < UPL; ++q) {
            float v0 = acc[2 * q] * dc;
            float v1 = acc[2 * q + 1] * dc;
            o[q] = (unsigned)f2bf(v0) | ((unsigned)f2bf(v1) << 16);
        }
    } else {
        float* o = (float*)out + (size_t)node * (RW * 2) + lane * (UPL * 2);
#pragma unroll
        for (int q = 0; q < UPL; ++q) {
            float b0v = BIAS ? bias[(lane * UPL + q) * 2 + 0] : 0.f;
            float b1v = BIAS ? bias[(lane * UPL + q) * 2 + 1] : 0.f;
            o[2 * q]     = acc[2 * q] * dc + b0v;
            o[2 * q + 1] = acc[2 * q + 1] * dc + b1v;
        }
    }
}

// ----------------------------- MFMA GEMM (B in regs) ------------------------
// C[Nrows,Dout] = A[Nrows,K] @ W (+bias)(+relu); A,Wt,C bf16; Wt=[Dout][K].
// Block = 4 waves, all sharing the 64-col panel n0; wave w owns 64 rows.
// Wave holds the ENTIRE B panel (64 x K) in VGPRs: 4 n-tiles x K/32 frags.
// A frags load global->VGPR (16 rows x 64B contiguous per wave-instruction).
// No LDS, no __syncthreads, K-loop fully unrolled, 1-step A prefetch.
// Frag conv (verified in R2/R3 kernel): mfma(Afrag{m=lane&15,k=q*8+j},
//   Bfrag{n=lane&15,k=q*8+j}) -> C{col=lane&15,row=q*4+reg}.
template<int K, bool RELU, bool BIAS>
__global__ __launch_bounds__(256, 2) void gemm_breg(const unsigned short* __restrict__ A,
                                                    const unsigned short* __restrict__ Wt,
                                                    const float* __restrict__ bias,
                                                    unsigned short* __restrict__ C,
                                                    int Nrows, int Dout) {
    constexpr int KS = K / 32;
    int t = threadIdx.x;
    int w = t >> 6, lane = t & 63;
    int lrow = lane & 15, lkq = lane >> 4;
    int n0 = blockIdx.x << 6;
    int mb = blockIdx.y * 256 + w * 64;

    // Load full B panel into registers (shared-value across the 4 waves).
    bf16x8 bf[4][KS];
#pragma unroll
    for (int j = 0; j < 4; ++j) {
        const unsigned short* bp = Wt + (size_t)(n0 + j * 16 + lrow) * K + lkq * 8;
#pragma unroll
        for (int s = 0; s < KS; ++s) bf[j][s] = *(const bf16x8*)(bp + s * 32);
    }

    // Per-lane A row base pointers (clamped for the tail M-tile).
    const unsigned short* ap[4];
#pragma unroll
    for (int i = 0; i < 4; ++i) {
        int r = mb + i * 16 + lrow;
        r = min(r, Nrows - 1);
        ap[i] = A + (size_t)r * K + lkq * 8;
    }

    f32x4 acc[4][4];
#pragma unroll
    for (int i = 0; i < 4; ++i)
#pragma unroll
        for (int j = 0; j < 4; ++j) acc[i][j] = (f32x4){0.f, 0.f, 0.f, 0.f};

    bf16x8 a0[4], a1[4];
#pragma unroll
    for (int i = 0; i < 4; ++i) a0[i] = *(const bf16x8*)(ap[i]);
#pragma unroll
    for (int s = 0; s < KS; ++s) {
        bf16x8* cur = (s & 1) ? a1 : a0;
        bf16x8* nxt = (s & 1) ? a0 : a1;
        if (s + 1 < KS) {
#pragma unroll
            for (int i = 0; i < 4; ++i) nxt[i] = *(const bf16x8*)(ap[i] + (s + 1) * 32);
        }
#pragma unroll
        for (int i = 0; i < 4; ++i)
#pragma unroll
            for (int j = 0; j < 4; ++j)
                acc[i][j] = __builtin_amdgcn_mfma_f32_16x16x32_bf16(
                    cur[i], bf[j][s], acc[i][j], 0, 0, 0);
    }

#pragma unroll
    for (int j = 0; j < 4; ++j) {
        int colc = n0 + j * 16 + lrow;
        float bj = BIAS ? bias[colc] : 0.f;
#pragma unroll
        for (int i = 0; i < 4; ++i) {
            int rb = mb + i * 16 + (lkq << 2);
#pragma unroll
            for (int r = 0; r < 4; ++r) {
                int rowc = rb + r;
                if (rowc < Nrows) {
                    float v = acc[i][j][r] + bj;
                    if (RELU) v = fmaxf(v, 0.f);
                    C[(size_t)rowc * Dout + colc] = f2bf(v);
                }
            }
        }
    }
}

// ----------------------------- launch --------------------------------------

extern "C" void kernel_launch(void* const* d_in, const int* in_sizes, int n_in,
                              void* d_out, int out_size, void* d_ws, size_t ws_size,
                              hipStream_t stream) {
    const float* x  = (const float*)d_in[0];
    const int*   ei = (const int*)d_in[1];
    const float* W0 = (const float*)d_in[4];
    const float* b0 = (const float*)d_in[5];
    const float* W1 = (const float*)d_in[6];
    const float* b1 = (const float*)d_in[7];
    const float* W2 = (const float*)d_in[8];
    const float* b2 = (const float*)d_in[9];

    const int N = in_sizes[0] / 128;
    const int E = in_sizes[1] / 2;
    const int* row = ei;       // sources
    const int* col = ei + E;   // destinations

    char* wp = (char*)d_ws;
    auto carve = [&](size_t bytes) {
        void* p = (void*)wp;
        wp += (bytes + 255) & ~(size_t)255;
        return p;
    };
    const int NB = (N + 2047) / 2048;
    int*   cnt    = (int*)carve((size_t)N * 4);
    int*   offs   = (int*)carve((size_t)(N + 1) * 4);
    int*   cursor = (int*)carve((size_t)N * 4);
    int*   esrc   = (int*)carve((size_t)E * 4);
    float* dinv   = (float*)carve((size_t)N * 4);
    int*   bsums  = (int*)carve((size_t)NB * 4);
    unsigned short* Wt0 = (unsigned short*)carve((size_t)256 * 128 * 2);
    unsigned short* Wt1 = (unsigned short*)carve((size_t)256 * 256 * 2);
    unsigned short* Wt2 = (unsigned short*)carve((size_t)128 * 256 * 2);
    // regionX (N*256 bf16): xb | agg0b, later reused whole as h2b
    unsigned short* regX = (unsigned short*)carve((size_t)N * 256 * 2);
    unsigned short* xb    = regX;                       // N*128 bf16
    unsigned short* agg0b = regX + (size_t)N * 128;     // N*128 bf16
    unsigned short* h2b   = regX;                       // N*256 (agg0b dead by then)
    unsigned short* h1b = (unsigned short*)carve((size_t)N * 256 * 2);
    unsigned short* hwb = h1b;                          // N*128 (h1b dead by then)
    unsigned short* agg1b = (unsigned short*)carve((size_t)N * 256 * 2);

    // --- CSR build ---
    hipMemsetAsync(cnt, 0, (size_t)N * 4, stream);
    count_edges<<<(E + 255) / 256, 256, 0, stream>>>(col, E, cnt);
    scan_reduce<<<NB, 256, 0, stream>>>(cnt, N, bsums);
    scan_finish<<<NB, 256, 0, stream>>>(cnt, N, bsums, NB, offs, cursor, dinv);
    fill_csr<<<(E + 255) / 256, 256, 0, stream>>>(row, col, E, cursor, esrc);

    // --- fused converts ---
    {
        int n4 = N * 128 / 4;
        int tot = n4 + 32768 + 65536 + 32768;
        conv_fused<<<(tot + 255) / 256, 256, 0, stream>>>(
            (const float4*)x, (uint2*)xb, n4, W0, W1, W2, Wt0, Wt1, Wt2);
    }

    const int aggBlocks = (N + 3) / 4;  // 1 node/wave
    const int mTiles = (N + 255) / 256;

    // L0: agg0 = Â xb ; h1 = relu(agg0 @ W0 + b0)
    aggregate_bf<1, true, false><<<aggBlocks, 256, 0, stream>>>(
        (const unsigned*)xb, dinv, offs, esrc, nullptr, agg0b, N);
    gemm_breg<128, true, true><<<dim3(4, mTiles), 256, 0, stream>>>(
        agg0b, Wt0, b0, h1b, N, 256);
    // L1: agg1 = Â h1 ; h2 = relu(agg1 @ W1 + b1)
    aggregate_bf<2, true, false><<<aggBlocks, 256, 0, stream>>>(
        (const unsigned*)h1b, dinv, offs, esrc, nullptr, agg1b, N);
    gemm_breg<256, true, true><<<dim3(4, mTiles), 256, 0, stream>>>(
        agg1b, Wt1, b1, h2b, N, 256);
    // L2: hw = h2 @ W2 ; out = Â hw + b2 (fp32)
    gemm_breg<256, false, false><<<dim3(2, mTiles), 256, 0, stream>>>(
        h2b, Wt2, nullptr, hwb, N, 128);
    aggregate_bf<1, false, true><<<aggBlocks, 256, 0, stream>>>(
        (const unsigned*)hwb, dinv, offs, esrc, b2, d_out, N);
}

// Round 5
// 685.760 us; speedup vs baseline: 1.1777x; 1.1777x over previous
//
#include <hip/hip_runtime.h>

// ---------------------------------------------------------------------------
// GCN, bf16 pipeline.
//  - Aggregation: CSR gather, lane-grouped 16B/lane loads (D=128: 4 edges per
//    load instr, D=256: 2), cross-group shuffle reduce. Maximizes in-flight
//    gather bytes per wave (R4 profile: 45% HBM, VALU 33% -> parallelism-bound).
//  - GEMMs: R3's LDS fragment-major MFMA (R4 falsified B-in-regs variant).
// ---------------------------------------------------------------------------

typedef __attribute__((ext_vector_type(8))) short bf16x8;
typedef __attribute__((ext_vector_type(4))) float f32x4;

__device__ __forceinline__ float bf_lo(unsigned u) {
    union { unsigned i; float f; } x; x.i = u << 16; return x.f;
}
__device__ __forceinline__ float bf_hi(unsigned u) {
    union { unsigned i; float f; } x; x.i = u & 0xFFFF0000u; return x.f;
}
__device__ __forceinline__ unsigned short f2bf(float f) {  // RNE
    union { float f; unsigned i; } x; x.f = f;
    unsigned r = x.i + 0x7FFFu + ((x.i >> 16) & 1u);
    return (unsigned short)(r >> 16);
}

// ----------------------------- CSR build -----------------------------------

__global__ __launch_bounds__(256) void count_edges(const int* __restrict__ col,
                                                   int E, int* __restrict__ cnt) {
    int e = blockIdx.x * 256 + threadIdx.x;
    if (e < E) atomicAdd(&cnt[col[e]], 1);
}

__global__ __launch_bounds__(256) void scan_reduce(const int* __restrict__ cnt, int Nn,
                                                   int* __restrict__ blockSums) {
    __shared__ int s[256];
    int t = threadIdx.x;
    int base = blockIdx.x * 2048 + t * 8;
    int v = 0;
#pragma unroll
    for (int j = 0; j < 8; ++j) {
        int i = base + j;
        if (i < Nn) v += cnt[i];
    }
    s[t] = v;
    __syncthreads();
    for (int off = 128; off > 0; off >>= 1) {
        if (t < off) s[t] += s[t + off];
        __syncthreads();
    }
    if (t == 0) blockSums[blockIdx.x] = s[0];
}

__global__ __launch_bounds__(256) void scan_finish(const int* __restrict__ cnt, int Nn,
                                                   const int* __restrict__ blockSums, int nb,
                                                   int* __restrict__ offs,
                                                   int* __restrict__ cursor,
                                                   float* __restrict__ dinv) {
    __shared__ int s[256];
    __shared__ int basePrefix;
    int t = threadIdx.x;
    if (t == 0) {
        int p = 0;
        for (int i = 0; i < (int)blockIdx.x; ++i) p += blockSums[i];
        basePrefix = p;
    }
    int base = blockIdx.x * 2048 + t * 8;
    int c[8];
    int sum = 0;
#pragma unroll
    for (int j = 0; j < 8; ++j) {
        int i = base + j;
        c[j] = (i < Nn) ? cnt[i] : 0;
        sum += c[j];
    }
    s[t] = sum;
    __syncthreads();
    for (int off = 1; off < 256; off <<= 1) {
        int v = (t >= off) ? s[t - off] : 0;
        __syncthreads();
        s[t] += v;
        __syncthreads();
    }
    int run = ((t > 0) ? s[t - 1] : 0) + basePrefix;
#pragma unroll
    for (int j = 0; j < 8; ++j) {
        int i = base + j;
        if (i < Nn) {
            offs[i] = run;
            cursor[i] = run;
            dinv[i] = rsqrtf((float)(c[j] + 1));  // +1 self loop
            run += c[j];
        }
    }
    if (blockIdx.x == (unsigned)(nb - 1) && t == 255) offs[Nn] = basePrefix + s[255];
}

__global__ __launch_bounds__(256) void fill_csr(const int* __restrict__ row,
                                                const int* __restrict__ col, int E,
                                                int* __restrict__ cursor,
                                                int* __restrict__ esrc) {
    int e = blockIdx.x * 256 + threadIdx.x;
    if (e < E) {
        int pos = atomicAdd(&cursor[col[e]], 1);
        esrc[pos] = row[e];
    }
}

// --------------------- fused converts (x + 3 weights) -----------------------

__global__ __launch_bounds__(256) void conv_fused(const float4* __restrict__ x4,
                                                  uint2* __restrict__ xb, int n4,
                                                  const float* __restrict__ W0,
                                                  const float* __restrict__ W1,
                                                  const float* __restrict__ W2,
                                                  unsigned short* __restrict__ Wt0,
                                                  unsigned short* __restrict__ Wt1,
                                                  unsigned short* __restrict__ Wt2) {
    int i = blockIdx.x * 256 + threadIdx.x;
    if (i < n4) {
        float4 v = x4[i];
        uint2 o;
        o.x = (unsigned)f2bf(v.x) | ((unsigned)f2bf(v.y) << 16);
        o.y = (unsigned)f2bf(v.z) | ((unsigned)f2bf(v.w) << 16);
        xb[i] = o;
        return;
    }
    int j = i - n4;
    if (j < 32768) {                        // Wt0[n*128+k] = W0[k*256+n]
        int n = j >> 7, k = j & 127;
        Wt0[j] = f2bf(W0[(size_t)k * 256 + n]);
    } else if (j < 32768 + 65536) {         // Wt1[n*256+k] = W1[k*256+n]
        int q = j - 32768;
        int n = q >> 8, k = q & 255;
        Wt1[q] = f2bf(W1[(size_t)k * 256 + n]);
    } else if (j < 32768 + 65536 + 32768) { // Wt2[n*256+k] = W2[k*128+n]
        int q = j - 98304;
        int n = q >> 8, k = q & 255;
        Wt2[q] = f2bf(W2[(size_t)k * 128 + n]);
    }
}

// ----------------------------- aggregation ---------------------------------
// One wave per dest node. Lane-grouped gathers: G = 512/D groups, L = 64/G
// lanes per row, each lane loads uint4 (16B = 8 bf16 feats). Group g handles
// edges e0+g, e0+g+G, ... (2 per loop iter). Cross-group shfl_xor reduce.
// out[c] = dinv[c] * ( dinv[c]*h[c] + sum_s dinv[s]*h[s] ) [+ bias]
template<int DFEAT, bool OUTBF, bool BIAS>
__global__ __launch_bounds__(256) void aggregate_g(const unsigned* __restrict__ hb,
                                                   const float* __restrict__ dinv,
                                                   const int* __restrict__ offs,
                                                   const int* __restrict__ esrc,
                                                   const float* __restrict__ bias,
                                                   void* __restrict__ out, int Nn) {
    constexpr int RW = DFEAT / 2;    // uints per row
    constexpr int G  = 512 / DFEAT;  // edges per load instr (128->4, 256->2)
    constexpr int L  = 64 / G;       // lanes per row
    int node = (int)((blockIdx.x * 256u + threadIdx.x) >> 6);
    if (node >= Nn) return;
    int lane = threadIdx.x & 63;
    int grp = lane / L;
    int lid = lane % L;  // lane's 16B slot within a row

    float acc[8];
    if (grp == 0) {  // self-loop term, group 0 only (fixed up by reduction)
        float dc0 = dinv[node];
        uint4 u = *(const uint4*)(hb + (size_t)node * RW + lid * 4);
        const unsigned* up = (const unsigned*)&u;
#pragma unroll
        for (int q = 0; q < 4; ++q) {
            acc[2 * q]     = dc0 * bf_lo(up[q]);
            acc[2 * q + 1] = dc0 * bf_hi(up[q]);
        }
    } else {
#pragma unroll
        for (int q = 0; q < 8; ++q) acc[q] = 0.f;
    }

    int e0 = offs[node], e1 = offs[node + 1];
    int k = e0 + grp;
    while (k + G < e1) {  // edges k and k+G both valid for this group
        int s0 = esrc[k], s1 = esrc[k + G];
        float d0 = dinv[s0], d1 = dinv[s1];
        uint4 u0 = *(const uint4*)(hb + (size_t)s0 * RW + lid * 4);
        uint4 u1 = *(const uint4*)(hb + (size_t)s1 * RW + lid * 4);
        const unsigned* u0p = (const unsigned*)&u0;
        const unsigned* u1p = (const unsigned*)&u1;
#pragma unroll
        for (int q = 0; q < 4; ++q) {
            acc[2 * q]     = fmaf(d0, bf_lo(u0p[q]), acc[2 * q]);
            acc[2 * q + 1] = fmaf(d0, bf_hi(u0p[q]), acc[2 * q + 1]);
            acc[2 * q]     = fmaf(d1, bf_lo(u1p[q]), acc[2 * q]);
            acc[2 * q + 1] = fmaf(d1, bf_hi(u1p[q]), acc[2 * q + 1]);
        }
        k += 2 * G;
    }
    if (k < e1) {
        int s0 = esrc[k];
        float d0 = dinv[s0];
        uint4 u0 = *(const uint4*)(hb + (size_t)s0 * RW + lid * 4);
        const unsigned* u0p = (const unsigned*)&u0;
#pragma unroll
        for (int q = 0; q < 4; ++q) {
            acc[2 * q]     = fmaf(d0, bf_lo(u0p[q]), acc[2 * q]);
            acc[2 * q + 1] = fmaf(d0, bf_hi(u0p[q]), acc[2 * q + 1]);
        }
    }

    // cross-group reduction (groups hold same features at same lid)
#pragma unroll
    for (int q = 0; q < 8; ++q) {
        if (G == 4) {
            acc[q] += __shfl_xor(acc[q], 16, 64);
            acc[q] += __shfl_xor(acc[q], 32, 64);
        } else {
            acc[q] += __shfl_xor(acc[q], 32, 64);
        }
    }

    float dc = dinv[node];
    if (grp == 0) {
        if (OUTBF) {
            uint4 o;
            unsigned* op = (unsigned*)&o;
#pragma unroll
            for (int q = 0; q < 4; ++q) {
                float v0 = acc[2 * q] * dc;
                float v1 = acc[2 * q + 1] * dc;
                op[q] = (unsigned)f2bf(v0) | ((unsigned)f2bf(v1) << 16);
            }
            *(uint4*)((unsigned*)out + (size_t)node * RW + lid * 4) = o;
        } else {
            float4 o0, o1;
            float* o0p = (float*)&o0;
            float* o1p = (float*)&o1;
#pragma unroll
            for (int q = 0; q < 4; ++q) {
                float b0v = BIAS ? bias[lid * 8 + 2 * q] : 0.f;
                float b1v = BIAS ? bias[lid * 8 + 2 * q + 1] : 0.f;
                float v0 = acc[2 * q] * dc + b0v;
                float v1 = acc[2 * q + 1] * dc + b1v;
                if (q < 2) { o0p[2 * q] = v0; o0p[2 * q + 1] = v1; }
                else       { o1p[2 * (q - 2)] = v0; o1p[2 * (q - 2) + 1] = v1; }
            }
            float* ob = (float*)out + (size_t)node * DFEAT + lid * 8;
            *(float4*)ob = o0;
            *(float4*)(ob + 4) = o1;
        }
    }
}

// ----------------------------- MFMA GEMM (R3 structure) ---------------------
// C[Nrows,Dout] = A[Nrows,K]@W[K,Dout] (+bias)(+relu), A/Wt bf16, C bf16.
// 128x128 tile / 4 waves. LDS fragment-major, staged via global_load_lds w=16.
// Frag layouts (m89/m91): A: m=lane&15,k=(lane>>4)*8+j; B same; C: col=lane&15,
// row=(lane>>4)*4+reg.
template<int K, bool RELU, bool BIAS>
__global__ __launch_bounds__(256) void gemm_mfma(const unsigned short* __restrict__ A,
                                                 const unsigned short* __restrict__ Bt,
                                                 const float* __restrict__ bias,
                                                 unsigned short* __restrict__ C,
                                                 int Nrows, int Dout) {
    __shared__ __align__(16) unsigned short As[8 * 64 * 8];  // 8KB
    __shared__ __align__(16) unsigned short Bs[8 * 64 * 8];  // 8KB
    int t = threadIdx.x;
    int w = t >> 6, lane = t & 63;
    int lrow = lane & 15, lkq = lane >> 4;
    int wr = w >> 1, wc = w & 1;
    int m0 = blockIdx.y << 7;
    int n0 = blockIdx.x << 7;

    int at0 = 2 * w, at1 = 2 * w + 1;
    int ar0 = min(m0 + at0 * 16 + lrow, Nrows - 1);
    int ar1 = min(m0 + at1 * 16 + lrow, Nrows - 1);
    const unsigned short* agp0 = A + (size_t)ar0 * K + lkq * 8;
    const unsigned short* agp1 = A + (size_t)ar1 * K + lkq * 8;
    const unsigned short* bgp0 = Bt + (size_t)(n0 + at0 * 16 + lrow) * K + lkq * 8;
    const unsigned short* bgp1 = Bt + (size_t)(n0 + at1 * 16 + lrow) * K + lkq * 8;
    unsigned short* asl0 = &As[at0 * 512];
    unsigned short* asl1 = &As[at1 * 512];
    unsigned short* bsl0 = &Bs[at0 * 512];
    unsigned short* bsl1 = &Bs[at1 * 512];

    f32x4 acc[4][4];
#pragma unroll
    for (int i = 0; i < 4; ++i)
#pragma unroll
        for (int j = 0; j < 4; ++j) acc[i][j] = (f32x4){0.f, 0.f, 0.f, 0.f};

    for (int k0 = 0; k0 < K; k0 += 32) {
        __syncthreads();
        __builtin_amdgcn_global_load_lds(
            (const __attribute__((address_space(1))) void*)(agp0 + k0),
            (__attribute__((address_space(3))) void*)asl0, 16, 0, 0);
        __builtin_amdgcn_global_load_lds(
            (const __attribute__((address_space(1))) void*)(agp1 + k0),
            (__attribute__((address_space(3))) void*)asl1, 16, 0, 0);
        __builtin_amdgcn_global_load_lds(
            (const __attribute__((address_space(1))) void*)(bgp0 + k0),
            (__attribute__((address_space(3))) void*)bsl0, 16, 0, 0);
        __builtin_amdgcn_global_load_lds(
            (const __attribute__((address_space(1))) void*)(bgp1 + k0),
            (__attribute__((address_space(3))) void*)bsl1, 16, 0, 0);
        __syncthreads();
        bf16x8 af[4], bfr[4];
#pragma unroll
        for (int i = 0; i < 4; ++i)
            af[i] = *(const bf16x8*)&As[(((wr * 4 + i) * 64) + lane) * 8];
#pragma unroll
        for (int j = 0; j < 4; ++j)
            bfr[j] = *(const bf16x8*)&Bs[(((wc * 4 + j) * 64) + lane) * 8];
#pragma unroll
        for (int i = 0; i < 4; ++i)
#pragma unroll
            for (int j = 0; j < 4; ++j)
                acc[i][j] = __builtin_amdgcn_mfma_f32_16x16x32_bf16(
                    af[i], bfr[j], acc[i][j], 0, 0, 0);
    }

#pragma unroll
    for (int j = 0; j < 4; ++j) {
        int col = n0 + ((wc * 4 + j) << 4) + lrow;
        float bj = BIAS ? bias[col] : 0.f;
#pragma unroll
        for (int i = 0; i < 4; ++i) {
            int rb = m0 + ((wr * 4 + i) << 4) + (lkq << 2);
            f32x4 c = acc[i][j];
#pragma unroll
            for (int r = 0; r < 4; ++r) {
                int row = rb + r;
                if (row < Nrows) {
                    float v = c[r] + bj;
                    if (RELU) v = fmaxf(v, 0.f);
                    C[(size_t)row * Dout + col] = f2bf(v);
                }
            }
        }
    }
}

// ----------------------------- launch --------------------------------------

extern "C" void kernel_launch(void* const* d_in, const int* in_sizes, int n_in,
                              void* d_out, int out_size, void* d_ws, size_t ws_size,
                              hipStream_t stream) {
    const float* x  = (const float*)d_in[0];
    const int*   ei = (const int*)d_in[1];
    const float* W0 = (const float*)d_in[4];
    const float* b0 = (const float*)d_in[5];
    const float* W1 = (const float*)d_in[6];
    const float* b1 = (const float*)d_in[7];
    const float* W2 = (const float*)d_in[8];
    const float* b2 = (const float*)d_in[9];

    const int N = in_sizes[0] / 128;
    const int E = in_sizes[1] / 2;
    const int* row = ei;       // sources
    const int* col = ei + E;   // destinations

    char* wp = (char*)d_ws;
    auto carve = [&](size_t bytes) {
        void* p = (void*)wp;
        wp += (bytes + 255) & ~(size_t)255;
        return p;
    };
    const int NB = (N + 2047) / 2048;
    int*   cnt    = (int*)carve((size_t)N * 4);
    int*   offs   = (int*)carve((size_t)(N + 1) * 4);
    int*   cursor = (int*)carve((size_t)N * 4);
    int*   esrc   = (int*)carve((size_t)E * 4);
    float* dinv   = (float*)carve((size_t)N * 4);
    int*   bsums  = (int*)carve((size_t)NB * 4);
    unsigned short* Wt0 = (unsigned short*)carve((size_t)256 * 128 * 2);
    unsigned short* Wt1 = (unsigned short*)carve((size_t)256 * 256 * 2);
    unsigned short* Wt2 = (unsigned short*)carve((size_t)128 * 256 * 2);
    unsigned short* regX = (unsigned short*)carve((size_t)N * 256 * 2);
    unsigned short* xb    = regX;                    // N*128 bf16
    unsigned short* agg0b = regX + (size_t)N * 128;  // N*128 bf16
    unsigned short* h2b   = regX;                    // N*256 (agg0b dead by then)
    unsigned short* h1b = (unsigned short*)carve((size_t)N * 256 * 2);
    unsigned short* hwb = h1b;                       // N*128 (h1b dead by then)
    unsigned short* agg1b = (unsigned short*)carve((size_t)N * 256 * 2);

    // --- CSR build ---
    hipMemsetAsync(cnt, 0, (size_t)N * 4, stream);
    count_edges<<<(E + 255) / 256, 256, 0, stream>>>(col, E, cnt);
    scan_reduce<<<NB, 256, 0, stream>>>(cnt, N, bsums);
    scan_finish<<<NB, 256, 0, stream>>>(cnt, N, bsums, NB, offs, cursor, dinv);
    fill_csr<<<(E + 255) / 256, 256, 0, stream>>>(row, col, E, cursor, esrc);

    // --- fused converts ---
    {
        int n4 = N * 128 / 4;
        int tot = n4 + 32768 + 65536 + 32768;
        conv_fused<<<(tot + 255) / 256, 256, 0, stream>>>(
            (const float4*)x, (uint2*)xb, n4, W0, W1, W2, Wt0, Wt1, Wt2);
    }

    const int aggBlocks = (N + 3) / 4;  // 1 node/wave
    dim3 g2col(2, (N + 127) / 128);
    dim3 g1col(1, (N + 127) / 128);

    // L0: agg0 = Â xb ; h1 = relu(agg0 @ W0 + b0)
    aggregate_g<128, true, false><<<aggBlocks, 256, 0, stream>>>(
        (const unsigned*)xb, dinv, offs, esrc, nullptr, agg0b, N);
    gemm_mfma<128, true, true><<<g2col, 256, 0, stream>>>(agg0b, Wt0, b0, h1b, N, 256);
    // L1: agg1 = Â h1 ; h2 = relu(agg1 @ W1 + b1)
    aggregate_g<256, true, false><<<aggBlocks, 256, 0, stream>>>(
        (const unsigned*)h1b, dinv, offs, esrc, nullptr, agg1b, N);
    gemm_mfma<256, true, true><<<g2col, 256, 0, stream>>>(agg1b, Wt1, b1, h2b, N, 256);
    // L2: hw = h2 @ W2 ; out = Â hw + b2 (fp32)
    gemm_mfma<256, false, false><<<g1col, 256, 0, stream>>>(h2b, Wt2, nullptr, hwb, N, 128);
    aggregate_g<128, false, true><<<aggBlocks, 256, 0, stream>>>(
        (const unsigned*)hwb, dinv, offs, esrc, b2, d_out, N);
}

// Round 6
// 611.166 us; speedup vs baseline: 1.3214x; 1.1221x over previous
//
#include <hip/hip_runtime.h>

// ---------------------------------------------------------------------------
// GCN, bf16 pipeline.
//  - CSR build: count_edges emits per-edge rank (return of atomicAdd), so
//    fill_csr is atomic-free (R5 profile: fill_csr 126us latency-bound on the
//    cursor atomic RMW -> scatter chain).
//  - Aggregation: lane-grouped 16B/lane gathers, 4 edges in flight per group.
//  - GEMMs: R3/R5 proven LDS fragment-major MFMA.
// ---------------------------------------------------------------------------

typedef __attribute__((ext_vector_type(8))) short bf16x8;
typedef __attribute__((ext_vector_type(4))) float f32x4;

__device__ __forceinline__ float bf_lo(unsigned u) {
    union { unsigned i; float f; } x; x.i = u << 16; return x.f;
}
__device__ __forceinline__ float bf_hi(unsigned u) {
    union { unsigned i; float f; } x; x.i = u & 0xFFFF0000u; return x.f;
}
__device__ __forceinline__ unsigned short f2bf(float f) {  // RNE
    union { float f; unsigned i; } x; x.f = f;
    unsigned r = x.i + 0x7FFFu + ((x.i >> 16) & 1u);
    return (unsigned short)(r >> 16);
}

// ----------------------------- CSR build -----------------------------------

// 4 edges/thread; rank[e] = this edge's arrival index at its destination.
__global__ __launch_bounds__(256) void count_edges(const int* __restrict__ col,
                                                   int E, int* __restrict__ cnt,
                                                   unsigned short* __restrict__ rank) {
    int base = (blockIdx.x * 256 + threadIdx.x) * 4;
    if (base + 3 < E) {
        int4 c = *(const int4*)(col + base);
        ushort4 r;
        r.x = (unsigned short)atomicAdd(&cnt[c.x], 1);
        r.y = (unsigned short)atomicAdd(&cnt[c.y], 1);
        r.z = (unsigned short)atomicAdd(&cnt[c.z], 1);
        r.w = (unsigned short)atomicAdd(&cnt[c.w], 1);
        *(ushort4*)(rank + base) = r;
    } else {
        for (int e = base; e < E; ++e)
            rank[e] = (unsigned short)atomicAdd(&cnt[col[e]], 1);
    }
}

__global__ __launch_bounds__(256) void scan_reduce(const int* __restrict__ cnt, int Nn,
                                                   int* __restrict__ blockSums) {
    __shared__ int s[256];
    int t = threadIdx.x;
    int base = blockIdx.x * 2048 + t * 8;
    int v = 0;
#pragma unroll
    for (int j = 0; j < 8; ++j) {
        int i = base + j;
        if (i < Nn) v += cnt[i];
    }
    s[t] = v;
    __syncthreads();
    for (int off = 128; off > 0; off >>= 1) {
        if (t < off) s[t] += s[t + off];
        __syncthreads();
    }
    if (t == 0) blockSums[blockIdx.x] = s[0];
}

__global__ __launch_bounds__(256) void scan_finish(const int* __restrict__ cnt, int Nn,
                                                   const int* __restrict__ blockSums, int nb,
                                                   int* __restrict__ offs,
                                                   float* __restrict__ dinv) {
    __shared__ int s[256];
    __shared__ int basePrefix;
    int t = threadIdx.x;
    if (t == 0) {
        int p = 0;
        for (int i = 0; i < (int)blockIdx.x; ++i) p += blockSums[i];
        basePrefix = p;
    }
    int base = blockIdx.x * 2048 + t * 8;
    int c[8];
    int sum = 0;
#pragma unroll
    for (int j = 0; j < 8; ++j) {
        int i = base + j;
        c[j] = (i < Nn) ? cnt[i] : 0;
        sum += c[j];
    }
    s[t] = sum;
    __syncthreads();
    for (int off = 1; off < 256; off <<= 1) {
        int v = (t >= off) ? s[t - off] : 0;
        __syncthreads();
        s[t] += v;
        __syncthreads();
    }
    int run = ((t > 0) ? s[t - 1] : 0) + basePrefix;
#pragma unroll
    for (int j = 0; j < 8; ++j) {
        int i = base + j;
        if (i < Nn) {
            offs[i] = run;
            dinv[i] = rsqrtf((float)(c[j] + 1));  // +1 self loop
            run += c[j];
        }
    }
    if (blockIdx.x == (unsigned)(nb - 1) && t == 255) offs[Nn] = basePrefix + s[255];
}

// Atomic-free: slot = offs[dest] + rank[e]. 4 edges/thread for scatter MLP.
__global__ __launch_bounds__(256) void fill_csr(const int* __restrict__ row,
                                                const int* __restrict__ col,
                                                const unsigned short* __restrict__ rank,
                                                int E,
                                                const int* __restrict__ offs,
                                                int* __restrict__ esrc) {
    int base = (blockIdx.x * 256 + threadIdx.x) * 4;
    if (base + 3 < E) {
        int4 r = *(const int4*)(row + base);
        int4 c = *(const int4*)(col + base);
        ushort4 k = *(const ushort4*)(rank + base);
        int p0 = offs[c.x] + k.x;
        int p1 = offs[c.y] + k.y;
        int p2 = offs[c.z] + k.z;
        int p3 = offs[c.w] + k.w;
        esrc[p0] = r.x;
        esrc[p1] = r.y;
        esrc[p2] = r.z;
        esrc[p3] = r.w;
    } else {
        for (int e = base; e < E; ++e)
            esrc[offs[col[e]] + rank[e]] = row[e];
    }
}

// --------------------- fused converts (x + 3 weights) -----------------------

__global__ __launch_bounds__(256) void conv_fused(const float4* __restrict__ x4,
                                                  uint2* __restrict__ xb, int n4,
                                                  const float* __restrict__ W0,
                                                  const float* __restrict__ W1,
                                                  const float* __restrict__ W2,
                                                  unsigned short* __restrict__ Wt0,
                                                  unsigned short* __restrict__ Wt1,
                                                  unsigned short* __restrict__ Wt2) {
    int i = blockIdx.x * 256 + threadIdx.x;
    if (i < n4) {
        float4 v = x4[i];
        uint2 o;
        o.x = (unsigned)f2bf(v.x) | ((unsigned)f2bf(v.y) << 16);
        o.y = (unsigned)f2bf(v.z) | ((unsigned)f2bf(v.w) << 16);
        xb[i] = o;
        return;
    }
    int j = i - n4;
    if (j < 32768) {                        // Wt0[n*128+k] = W0[k*256+n]
        int n = j >> 7, k = j & 127;
        Wt0[j] = f2bf(W0[(size_t)k * 256 + n]);
    } else if (j < 32768 + 65536) {         // Wt1[n*256+k] = W1[k*256+n]
        int q = j - 32768;
        int n = q >> 8, k = q & 255;
        Wt1[q] = f2bf(W1[(size_t)k * 256 + n]);
    } else if (j < 32768 + 65536 + 32768) { // Wt2[n*256+k] = W2[k*128+n]
        int q = j - 98304;
        int n = q >> 8, k = q & 255;
        Wt2[q] = f2bf(W2[(size_t)k * 128 + n]);
    }
}

// ----------------------------- aggregation ---------------------------------
// One wave per dest node. G = 512/D lane-groups, L = 64/G lanes per row; each
// lane loads uint4 (16B). Group g handles edges e0+g, e0+g+G, ... with a
// 4-deep unrolled main loop (4 independent gathers in flight per group).
// out[c] = dinv[c] * ( dinv[c]*h[c] + sum_s dinv[s]*h[s] ) [+ bias]
template<int DFEAT, bool OUTBF, bool BIAS>
__global__ __launch_bounds__(256) void aggregate_g(const unsigned* __restrict__ hb,
                                                   const float* __restrict__ dinv,
                                                   const int* __restrict__ offs,
                                                   const int* __restrict__ esrc,
                                                   const float* __restrict__ bias,
                                                   void* __restrict__ out, int Nn) {
    constexpr int RW = DFEAT / 2;    // uints per row
    constexpr int G  = 512 / DFEAT;  // parallel edges (128->4, 256->2)
    constexpr int L  = 64 / G;       // lanes per row
    int node = (int)((blockIdx.x * 256u + threadIdx.x) >> 6);
    if (node >= Nn) return;
    int lane = threadIdx.x & 63;
    int grp = lane / L;
    int lid = lane % L;  // 16B slot within a row

    float acc[8];
    if (grp == 0) {  // self-loop term in group 0; folded by the reduction
        float dc0 = dinv[node];
        uint4 u = *(const uint4*)(hb + (size_t)node * RW + lid * 4);
        const unsigned* up = (const unsigned*)&u;
#pragma unroll
        for (int q = 0; q < 4; ++q) {
            acc[2 * q]     = dc0 * bf_lo(up[q]);
            acc[2 * q + 1] = dc0 * bf_hi(up[q]);
        }
    } else {
#pragma unroll
        for (int q = 0; q < 8; ++q) acc[q] = 0.f;
    }

    int e0 = offs[node], e1 = offs[node + 1];
    int k = e0 + grp;
    while (k + 3 * G < e1) {  // 4 edges for this group
        int s0 = esrc[k], s1 = esrc[k + G], s2 = esrc[k + 2 * G], s3 = esrc[k + 3 * G];
        float d0 = dinv[s0], d1 = dinv[s1], d2 = dinv[s2], d3 = dinv[s3];
        uint4 u0 = *(const uint4*)(hb + (size_t)s0 * RW + lid * 4);
        uint4 u1 = *(const uint4*)(hb + (size_t)s1 * RW + lid * 4);
        uint4 u2 = *(const uint4*)(hb + (size_t)s2 * RW + lid * 4);
        uint4 u3 = *(const uint4*)(hb + (size_t)s3 * RW + lid * 4);
        const unsigned* u0p = (const unsigned*)&u0;
        const unsigned* u1p = (const unsigned*)&u1;
        const unsigned* u2p = (const unsigned*)&u2;
        const unsigned* u3p = (const unsigned*)&u3;
#pragma unroll
        for (int q = 0; q < 4; ++q) {
            acc[2 * q]     = fmaf(d0, bf_lo(u0p[q]), acc[2 * q]);
            acc[2 * q + 1] = fmaf(d0, bf_hi(u0p[q]), acc[2 * q + 1]);
            acc[2 * q]     = fmaf(d1, bf_lo(u1p[q]), acc[2 * q]);
            acc[2 * q + 1] = fmaf(d1, bf_hi(u1p[q]), acc[2 * q + 1]);
            acc[2 * q]     = fmaf(d2, bf_lo(u2p[q]), acc[2 * q]);
            acc[2 * q + 1] = fmaf(d2, bf_hi(u2p[q]), acc[2 * q + 1]);
            acc[2 * q]     = fmaf(d3, bf_lo(u3p[q]), acc[2 * q]);
            acc[2 * q + 1] = fmaf(d3, bf_hi(u3p[q]), acc[2 * q + 1]);
        }
        k += 4 * G;
    }
    while (k < e1) {  // tail, 1 edge at a time
        int s0 = esrc[k];
        float d0 = dinv[s0];
        uint4 u0 = *(const uint4*)(hb + (size_t)s0 * RW + lid * 4);
        const unsigned* u0p = (const unsigned*)&u0;
#pragma unroll
        for (int q = 0; q < 4; ++q) {
            acc[2 * q]     = fmaf(d0, bf_lo(u0p[q]), acc[2 * q]);
            acc[2 * q + 1] = fmaf(d0, bf_hi(u0p[q]), acc[2 * q + 1]);
        }
        k += G;
    }

    // cross-group reduction (same features live at same lid in each group)
#pragma unroll
    for (int q = 0; q < 8; ++q) {
        if (G == 4) {
            acc[q] += __shfl_xor(acc[q], 16, 64);
            acc[q] += __shfl_xor(acc[q], 32, 64);
        } else {
            acc[q] += __shfl_xor(acc[q], 32, 64);
        }
    }

    float dc = dinv[node];
    if (grp == 0) {
        if (OUTBF) {
            uint4 o;
            unsigned* op = (unsigned*)&o;
#pragma unroll
            for (int q = 0; q < 4; ++q) {
                float v0 = acc[2 * q] * dc;
                float v1 = acc[2 * q + 1] * dc;
                op[q] = (unsigned)f2bf(v0) | ((unsigned)f2bf(v1) << 16);
            }
            *(uint4*)((unsigned*)out + (size_t)node * RW + lid * 4) = o;
        } else {
            float4 o0, o1;
            float* o0p = (float*)&o0;
            float* o1p = (float*)&o1;
#pragma unroll
            for (int q = 0; q < 4; ++q) {
                float b0v = BIAS ? bias[lid * 8 + 2 * q] : 0.f;
                float b1v = BIAS ? bias[lid * 8 + 2 * q + 1] : 0.f;
                float v0 = acc[2 * q] * dc + b0v;
                float v1 = acc[2 * q + 1] * dc + b1v;
                if (q < 2) { o0p[2 * q] = v0; o0p[2 * q + 1] = v1; }
                else       { o1p[2 * (q - 2)] = v0; o1p[2 * (q - 2) + 1] = v1; }
            }
            float* ob = (float*)out + (size_t)node * DFEAT + lid * 8;
            *(float4*)ob = o0;
            *(float4*)(ob + 4) = o1;
        }
    }
}

// ----------------------------- MFMA GEMM (R3 structure, proven) -------------
template<int K, bool RELU, bool BIAS>
__global__ __launch_bounds__(256) void gemm_mfma(const unsigned short* __restrict__ A,
                                                 const unsigned short* __restrict__ Bt,
                                                 const float* __restrict__ bias,
                                                 unsigned short* __restrict__ C,
                                                 int Nrows, int Dout) {
    __shared__ __align__(16) unsigned short As[8 * 64 * 8];  // 8KB
    __shared__ __align__(16) unsigned short Bs[8 * 64 * 8];  // 8KB
    int t = threadIdx.x;
    int w = t >> 6, lane = t & 63;
    int lrow = lane & 15, lkq = lane >> 4;
    int wr = w >> 1, wc = w & 1;
    int m0 = blockIdx.y << 7;
    int n0 = blockIdx.x << 7;

    int at0 = 2 * w, at1 = 2 * w + 1;
    int ar0 = min(m0 + at0 * 16 + lrow, Nrows - 1);
    int ar1 = min(m0 + at1 * 16 + lrow, Nrows - 1);
    const unsigned short* agp0 = A + (size_t)ar0 * K + lkq * 8;
    const unsigned short* agp1 = A + (size_t)ar1 * K + lkq * 8;
    const unsigned short* bgp0 = Bt + (size_t)(n0 + at0 * 16 + lrow) * K + lkq * 8;
    const unsigned short* bgp1 = Bt + (size_t)(n0 + at1 * 16 + lrow) * K + lkq * 8;
    unsigned short* asl0 = &As[at0 * 512];
    unsigned short* asl1 = &As[at1 * 512];
    unsigned short* bsl0 = &Bs[at0 * 512];
    unsigned short* bsl1 = &Bs[at1 * 512];

    f32x4 acc[4][4];
#pragma unroll
    for (int i = 0; i < 4; ++i)
#pragma unroll
        for (int j = 0; j < 4; ++j) acc[i][j] = (f32x4){0.f, 0.f, 0.f, 0.f};

    for (int k0 = 0; k0 < K; k0 += 32) {
        __syncthreads();
        __builtin_amdgcn_global_load_lds(
            (const __attribute__((address_space(1))) void*)(agp0 + k0),
            (__attribute__((address_space(3))) void*)asl0, 16, 0, 0);
        __builtin_amdgcn_global_load_lds(
            (const __attribute__((address_space(1))) void*)(agp1 + k0),
            (__attribute__((address_space(3))) void*)asl1, 16, 0, 0);
        __builtin_amdgcn_global_load_lds(
            (const __attribute__((address_space(1))) void*)(bgp0 + k0),
            (__attribute__((address_space(3))) void*)bsl0, 16, 0, 0);
        __builtin_amdgcn_global_load_lds(
            (const __attribute__((address_space(1))) void*)(bgp1 + k0),
            (__attribute__((address_space(3))) void*)bsl1, 16, 0, 0);
        __syncthreads();
        bf16x8 af[4], bfr[4];
#pragma unroll
        for (int i = 0; i < 4; ++i)
            af[i] = *(const bf16x8*)&As[(((wr * 4 + i) * 64) + lane) * 8];
#pragma unroll
        for (int j = 0; j < 4; ++j)
            bfr[j] = *(const bf16x8*)&Bs[(((wc * 4 + j) * 64) + lane) * 8];
#pragma unroll
        for (int i = 0; i < 4; ++i)
#pragma unroll
            for (int j = 0; j < 4; ++j)
                acc[i][j] = __builtin_amdgcn_mfma_f32_16x16x32_bf16(
                    af[i], bfr[j], acc[i][j], 0, 0, 0);
    }

#pragma unroll
    for (int j = 0; j < 4; ++j) {
        int col = n0 + ((wc * 4 + j) << 4) + lrow;
        float bj = BIAS ? bias[col] : 0.f;
#pragma unroll
        for (int i = 0; i < 4; ++i) {
            int rb = m0 + ((wr * 4 + i) << 4) + (lkq << 2);
            f32x4 c = acc[i][j];
#pragma unroll
            for (int r = 0; r < 4; ++r) {
                int row = rb + r;
                if (row < Nrows) {
                    float v = c[r] + bj;
                    if (RELU) v = fmaxf(v, 0.f);
                    C[(size_t)row * Dout + col] = f2bf(v);
                }
            }
        }
    }
}

// ----------------------------- launch --------------------------------------

extern "C" void kernel_launch(void* const* d_in, const int* in_sizes, int n_in,
                              void* d_out, int out_size, void* d_ws, size_t ws_size,
                              hipStream_t stream) {
    const float* x  = (const float*)d_in[0];
    const int*   ei = (const int*)d_in[1];
    const float* W0 = (const float*)d_in[4];
    const float* b0 = (const float*)d_in[5];
    const float* W1 = (const float*)d_in[6];
    const float* b1 = (const float*)d_in[7];
    const float* W2 = (const float*)d_in[8];
    const float* b2 = (const float*)d_in[9];

    const int N = in_sizes[0] / 128;
    const int E = in_sizes[1] / 2;
    const int* row = ei;       // sources
    const int* col = ei + E;   // destinations

    char* wp = (char*)d_ws;
    auto carve = [&](size_t bytes) {
        void* p = (void*)wp;
        wp += (bytes + 255) & ~(size_t)255;
        return p;
    };
    const int NB = (N + 2047) / 2048;
    int*   cnt    = (int*)carve((size_t)N * 4);
    int*   offs   = (int*)carve((size_t)(N + 1) * 4);
    unsigned short* rank = (unsigned short*)carve((size_t)E * 2);
    int*   esrc   = (int*)carve((size_t)E * 4);
    float* dinv   = (float*)carve((size_t)N * 4);
    int*   bsums  = (int*)carve((size_t)NB * 4);
    unsigned short* Wt0 = (unsigned short*)carve((size_t)256 * 128 * 2);
    unsigned short* Wt1 = (unsigned short*)carve((size_t)256 * 256 * 2);
    unsigned short* Wt2 = (unsigned short*)carve((size_t)128 * 256 * 2);
    unsigned short* regX = (unsigned short*)carve((size_t)N * 256 * 2);
    unsigned short* xb    = regX;                    // N*128 bf16
    unsigned short* agg0b = regX + (size_t)N * 128;  // N*128 bf16
    unsigned short* h2b   = regX;                    // N*256 (agg0b dead by then)
    unsigned short* h1b = (unsigned short*)carve((size_t)N * 256 * 2);
    unsigned short* hwb = h1b;                       // N*128 (h1b dead by then)
    unsigned short* agg1b = (unsigned short*)carve((size_t)N * 256 * 2);

    // --- CSR build ---
    hipMemsetAsync(cnt, 0, (size_t)N * 4, stream);
    count_edges<<<(E / 4 + 255) / 256, 256, 0, stream>>>(col, E, cnt, rank);
    scan_reduce<<<NB, 256, 0, stream>>>(cnt, N, bsums);
    scan_finish<<<NB, 256, 0, stream>>>(cnt, N, bsums, NB, offs, dinv);
    fill_csr<<<(E / 4 + 255) / 256, 256, 0, stream>>>(row, col, rank, E, offs, esrc);

    // --- fused converts ---
    {
        int n4 = N * 128 / 4;
        int tot = n4 + 32768 + 65536 + 32768;
        conv_fused<<<(tot + 255) / 256, 256, 0, stream>>>(
            (const float4*)x, (uint2*)xb, n4, W0, W1, W2, Wt0, Wt1, Wt2);
    }

    const int aggBlocks = (N + 3) / 4;  // 1 node/wave
    dim3 g2col(2, (N + 127) / 128);
    dim3 g1col(1, (N + 127) / 128);

    // L0: agg0 = Â xb ; h1 = relu(agg0 @ W0 + b0)
    aggregate_g<128, true, false><<<aggBlocks, 256, 0, stream>>>(
        (const unsigned*)xb, dinv, offs, esrc, nullptr, agg0b, N);
    gemm_mfma<128, true, true><<<g2col, 256, 0, stream>>>(agg0b, Wt0, b0, h1b, N, 256);
    // L1: agg1 = Â h1 ; h2 = relu(agg1 @ W1 + b1)
    aggregate_g<256, true, false><<<aggBlocks, 256, 0, stream>>>(
        (const unsigned*)h1b, dinv, offs, esrc, nullptr, agg1b, N);
    gemm_mfma<256, true, true><<<g2col, 256, 0, stream>>>(agg1b, Wt1, b1, h2b, N, 256);
    // L2: hw = h2 @ W2 ; out = Â hw + b2 (fp32)
    gemm_mfma<256, false, false><<<g1col, 256, 0, stream>>>(h2b, Wt2, nullptr, hwb, N, 128);
    aggregate_g<128, false, true><<<aggBlocks, 256, 0, stream>>>(
        (const unsigned*)hwb, dinv, offs, esrc, b2, d_out, N);
}

// Round 7
// 593.819 us; speedup vs baseline: 1.3600x; 1.0292x over previous
//
#include <hip/hip_runtime.h>

// ---------------------------------------------------------------------------
// GCN, bf16 pipeline.
//  - CSR: count (rank-emitting atomics) -> scan -> atomic-free fill.
//  - Aggregation: lane-grouped 16B/lane gathers (at ~3.9 TB/s random ceiling).
//  - GEMMs: B-panel-in-LDS persistent MFMA: one barrier per block, A streams
//    global->VGPR, B frags from padded LDS (2-way bank alias = free). Replaces
//    the R3 2-barrier-per-32K structure (inferred ~230us for 26 GFLOP).
// ---------------------------------------------------------------------------

typedef __attribute__((ext_vector_type(8))) short bf16x8;
typedef __attribute__((ext_vector_type(4))) float f32x4;

__device__ __forceinline__ float bf_lo(unsigned u) {
    union { unsigned i; float f; } x; x.i = u << 16; return x.f;
}
__device__ __forceinline__ float bf_hi(unsigned u) {
    union { unsigned i; float f; } x; x.i = u & 0xFFFF0000u; return x.f;
}
__device__ __forceinline__ unsigned short f2bf(float f) {  // RNE
    union { float f; unsigned i; } x; x.f = f;
    unsigned r = x.i + 0x7FFFu + ((x.i >> 16) & 1u);
    return (unsigned short)(r >> 16);
}

// ----------------------------- CSR build -----------------------------------

__global__ __launch_bounds__(256) void count_edges(const int* __restrict__ col,
                                                   int E, int* __restrict__ cnt,
                                                   unsigned short* __restrict__ rank) {
    int base = (blockIdx.x * 256 + threadIdx.x) * 4;
    if (base + 3 < E) {
        int4 c = *(const int4*)(col + base);
        ushort4 r;
        r.x = (unsigned short)atomicAdd(&cnt[c.x], 1);
        r.y = (unsigned short)atomicAdd(&cnt[c.y], 1);
        r.z = (unsigned short)atomicAdd(&cnt[c.z], 1);
        r.w = (unsigned short)atomicAdd(&cnt[c.w], 1);
        *(ushort4*)(rank + base) = r;
    } else {
        for (int e = base; e < E; ++e)
            rank[e] = (unsigned short)atomicAdd(&cnt[col[e]], 1);
    }
}

__global__ __launch_bounds__(256) void scan_reduce(const int* __restrict__ cnt, int Nn,
                                                   int* __restrict__ blockSums) {
    __shared__ int s[256];
    int t = threadIdx.x;
    int base = blockIdx.x * 2048 + t * 8;
    int v = 0;
#pragma unroll
    for (int j = 0; j < 8; ++j) {
        int i = base + j;
        if (i < Nn) v += cnt[i];
    }
    s[t] = v;
    __syncthreads();
    for (int off = 128; off > 0; off >>= 1) {
        if (t < off) s[t] += s[t + off];
        __syncthreads();
    }
    if (t == 0) blockSums[blockIdx.x] = s[0];
}

__global__ __launch_bounds__(256) void scan_finish(const int* __restrict__ cnt, int Nn,
                                                   const int* __restrict__ blockSums, int nb,
                                                   int* __restrict__ offs,
                                                   float* __restrict__ dinv) {
    __shared__ int s[256];
    __shared__ int basePrefix;
    int t = threadIdx.x;
    if (t == 0) {
        int p = 0;
        for (int i = 0; i < (int)blockIdx.x; ++i) p += blockSums[i];
        basePrefix = p;
    }
    int base = blockIdx.x * 2048 + t * 8;
    int c[8];
    int sum = 0;
#pragma unroll
    for (int j = 0; j < 8; ++j) {
        int i = base + j;
        c[j] = (i < Nn) ? cnt[i] : 0;
        sum += c[j];
    }
    s[t] = sum;
    __syncthreads();
    for (int off = 1; off < 256; off <<= 1) {
        int v = (t >= off) ? s[t - off] : 0;
        __syncthreads();
        s[t] += v;
        __syncthreads();
    }
    int run = ((t > 0) ? s[t - 1] : 0) + basePrefix;
#pragma unroll
    for (int j = 0; j < 8; ++j) {
        int i = base + j;
        if (i < Nn) {
            offs[i] = run;
            dinv[i] = rsqrtf((float)(c[j] + 1));  // +1 self loop
            run += c[j];
        }
    }
    if (blockIdx.x == (unsigned)(nb - 1) && t == 255) offs[Nn] = basePrefix + s[255];
}

__global__ __launch_bounds__(256) void fill_csr(const int* __restrict__ row,
                                                const int* __restrict__ col,
                                                const unsigned short* __restrict__ rank,
                                                int E,
                                                const int* __restrict__ offs,
                                                int* __restrict__ esrc) {
    int base = (blockIdx.x * 256 + threadIdx.x) * 4;
    if (base + 3 < E) {
        int4 r = *(const int4*)(row + base);
        int4 c = *(const int4*)(col + base);
        ushort4 k = *(const ushort4*)(rank + base);
        esrc[offs[c.x] + k.x] = r.x;
        esrc[offs[c.y] + k.y] = r.y;
        esrc[offs[c.z] + k.z] = r.z;
        esrc[offs[c.w] + k.w] = r.w;
    } else {
        for (int e = base; e < E; ++e)
            esrc[offs[col[e]] + rank[e]] = row[e];
    }
}

// --------------------- fused converts (x + 3 weights) -----------------------

__global__ __launch_bounds__(256) void conv_fused(const float4* __restrict__ x4,
                                                  uint2* __restrict__ xb, int n4,
                                                  const float* __restrict__ W0,
                                                  const float* __restrict__ W1,
                                                  const float* __restrict__ W2,
                                                  unsigned short* __restrict__ Wt0,
                                                  unsigned short* __restrict__ Wt1,
                                                  unsigned short* __restrict__ Wt2) {
    int i = blockIdx.x * 256 + threadIdx.x;
    if (i < n4) {
        float4 v = x4[i];
        uint2 o;
        o.x = (unsigned)f2bf(v.x) | ((unsigned)f2bf(v.y) << 16);
        o.y = (unsigned)f2bf(v.z) | ((unsigned)f2bf(v.w) << 16);
        xb[i] = o;
        return;
    }
    int j = i - n4;
    if (j < 32768) {                        // Wt0[n*128+k] = W0[k*256+n]
        int n = j >> 7, k = j & 127;
        Wt0[j] = f2bf(W0[(size_t)k * 256 + n]);
    } else if (j < 32768 + 65536) {         // Wt1[n*256+k] = W1[k*256+n]
        int q = j - 32768;
        int n = q >> 8, k = q & 255;
        Wt1[q] = f2bf(W1[(size_t)k * 256 + n]);
    } else if (j < 32768 + 65536 + 32768) { // Wt2[n*256+k] = W2[k*128+n]
        int q = j - 98304;
        int n = q >> 8, k = q & 255;
        Wt2[q] = f2bf(W2[(size_t)k * 128 + n]);
    }
}

// ----------------------------- aggregation (R6, proven) ---------------------
template<int DFEAT, bool OUTBF, bool BIAS>
__global__ __launch_bounds__(256) void aggregate_g(const unsigned* __restrict__ hb,
                                                   const float* __restrict__ dinv,
                                                   const int* __restrict__ offs,
                                                   const int* __restrict__ esrc,
                                                   const float* __restrict__ bias,
                                                   void* __restrict__ out, int Nn) {
    constexpr int RW = DFEAT / 2;    // uints per row
    constexpr int G  = 512 / DFEAT;  // parallel edges (128->4, 256->2)
    constexpr int L  = 64 / G;       // lanes per row
    int node = (int)((blockIdx.x * 256u + threadIdx.x) >> 6);
    if (node >= Nn) return;
    int lane = threadIdx.x & 63;
    int grp = lane / L;
    int lid = lane % L;

    float acc[8];
    if (grp == 0) {  // self-loop term; folded by the reduction
        float dc0 = dinv[node];
        uint4 u = *(const uint4*)(hb + (size_t)node * RW + lid * 4);
        const unsigned* up = (const unsigned*)&u;
#pragma unroll
        for (int q = 0; q < 4; ++q) {
            acc[2 * q]     = dc0 * bf_lo(up[q]);
            acc[2 * q + 1] = dc0 * bf_hi(up[q]);
        }
    } else {
#pragma unroll
        for (int q = 0; q < 8; ++q) acc[q] = 0.f;
    }

    int e0 = offs[node], e1 = offs[node + 1];
    int k = e0 + grp;
    while (k + 3 * G < e1) {
        int s0 = esrc[k], s1 = esrc[k + G], s2 = esrc[k + 2 * G], s3 = esrc[k + 3 * G];
        float d0 = dinv[s0], d1 = dinv[s1], d2 = dinv[s2], d3 = dinv[s3];
        uint4 u0 = *(const uint4*)(hb + (size_t)s0 * RW + lid * 4);
        uint4 u1 = *(const uint4*)(hb + (size_t)s1 * RW + lid * 4);
        uint4 u2 = *(const uint4*)(hb + (size_t)s2 * RW + lid * 4);
        uint4 u3 = *(const uint4*)(hb + (size_t)s3 * RW + lid * 4);
        const unsigned* u0p = (const unsigned*)&u0;
        const unsigned* u1p = (const unsigned*)&u1;
        const unsigned* u2p = (const unsigned*)&u2;
        const unsigned* u3p = (const unsigned*)&u3;
#pragma unroll
        for (int q = 0; q < 4; ++q) {
            acc[2 * q]     = fmaf(d0, bf_lo(u0p[q]), acc[2 * q]);
            acc[2 * q + 1] = fmaf(d0, bf_hi(u0p[q]), acc[2 * q + 1]);
            acc[2 * q]     = fmaf(d1, bf_lo(u1p[q]), acc[2 * q]);
            acc[2 * q + 1] = fmaf(d1, bf_hi(u1p[q]), acc[2 * q + 1]);
            acc[2 * q]     = fmaf(d2, bf_lo(u2p[q]), acc[2 * q]);
            acc[2 * q + 1] = fmaf(d2, bf_hi(u2p[q]), acc[2 * q + 1]);
            acc[2 * q]     = fmaf(d3, bf_lo(u3p[q]), acc[2 * q]);
            acc[2 * q + 1] = fmaf(d3, bf_hi(u3p[q]), acc[2 * q + 1]);
        }
        k += 4 * G;
    }
    while (k < e1) {
        int s0 = esrc[k];
        float d0 = dinv[s0];
        uint4 u0 = *(const uint4*)(hb + (size_t)s0 * RW + lid * 4);
        const unsigned* u0p = (const unsigned*)&u0;
#pragma unroll
        for (int q = 0; q < 4; ++q) {
            acc[2 * q]     = fmaf(d0, bf_lo(u0p[q]), acc[2 * q]);
            acc[2 * q + 1] = fmaf(d0, bf_hi(u0p[q]), acc[2 * q + 1]);
        }
        k += G;
    }

#pragma unroll
    for (int q = 0; q < 8; ++q) {
        if (G == 4) {
            acc[q] += __shfl_xor(acc[q], 16, 64);
            acc[q] += __shfl_xor(acc[q], 32, 64);
        } else {
            acc[q] += __shfl_xor(acc[q], 32, 64);
        }
    }

    float dc = dinv[node];
    if (grp == 0) {
        if (OUTBF) {
            uint4 o;
            unsigned* op = (unsigned*)&o;
#pragma unroll
            for (int q = 0; q < 4; ++q) {
                float v0 = acc[2 * q] * dc;
                float v1 = acc[2 * q + 1] * dc;
                op[q] = (unsigned)f2bf(v0) | ((unsigned)f2bf(v1) << 16);
            }
            *(uint4*)((unsigned*)out + (size_t)node * RW + lid * 4) = o;
        } else {
            float4 o0, o1;
            float* o0p = (float*)&o0;
            float* o1p = (float*)&o1;
#pragma unroll
            for (int q = 0; q < 4; ++q) {
                float b0v = BIAS ? bias[lid * 8 + 2 * q] : 0.f;
                float b1v = BIAS ? bias[lid * 8 + 2 * q + 1] : 0.f;
                float v0 = acc[2 * q] * dc + b0v;
                float v1 = acc[2 * q + 1] * dc + b1v;
                if (q < 2) { o0p[2 * q] = v0; o0p[2 * q + 1] = v1; }
                else       { o1p[2 * (q - 2)] = v0; o1p[2 * (q - 2) + 1] = v1; }
            }
            float* ob = (float*)out + (size_t)node * DFEAT + lid * 8;
            *(float4*)ob = o0;
            *(float4*)(ob + 4) = o1;
        }
    }
}

// --------------------- MFMA GEMM: B panel in LDS, persistent M --------------
// C[Nrows,Dout] = A[Nrows,K]@W (+bias)(+relu); A,Wt,C bf16; Wt=[Dout][K].
// Block: 4 waves (2x2), 128x128 tile, loops M-tiles (stride gridDim.y*128).
// B panel (128 cols x K) loaded into LDS ONCE (rows padded +8 halves so frag
// ds_read_b128 is 2-way bank-aliased = free), then the K-loop has NO barriers:
// A frags stream global->VGPR (16 rows x 64B dense lines), B frags from LDS.
// Frag maps (verified R3-R6): A/B: idx=lane&15, k=(lane>>4)*8+j;
//                             C: col=lane&15, row=(lane>>4)*4+reg.
template<int K, bool RELU, bool BIAS>
__global__ __launch_bounds__(256) void gemm_blds(const unsigned short* __restrict__ A,
                                                 const unsigned short* __restrict__ Wt,
                                                 const float* __restrict__ bias,
                                                 unsigned short* __restrict__ C,
                                                 int Nrows, int Dout) {
    constexpr int KP = K + 8;  // padded row stride (halves)
    __shared__ __align__(16) unsigned short Bsh[128 * KP];
    int t = threadIdx.x;
    int n0 = blockIdx.x << 7;

    // One-time B panel load (Dout is a multiple of 128 -> no tail).
    constexpr int CHUNKS = 128 * (K / 8);
    for (int c = t; c < CHUNKS; c += 256) {
        int rown = c / (K / 8);
        int kc = c - rown * (K / 8);
        *(bf16x8*)&Bsh[rown * KP + kc * 8] =
            *(const bf16x8*)&Wt[(size_t)(n0 + rown) * K + kc * 8];
    }
    __syncthreads();

    int w = t >> 6, lane = t & 63;
    int lrow = lane & 15, lkq = lane >> 4;
    int wr = w >> 1, wc = w & 1;
    const unsigned short* bbase = &Bsh[(wc * 64 + lrow) * KP + lkq * 8];

    for (int m0 = blockIdx.y * 128; m0 < Nrows; m0 += gridDim.y * 128) {
        f32x4 acc[4][4];
#pragma unroll
        for (int i = 0; i < 4; ++i)
#pragma unroll
            for (int j = 0; j < 4; ++j) acc[i][j] = (f32x4){0.f, 0.f, 0.f, 0.f};

        const unsigned short* ap[4];
#pragma unroll
        for (int i = 0; i < 4; ++i) {
            int r = min(m0 + wr * 64 + i * 16 + lrow, Nrows - 1);
            ap[i] = A + (size_t)r * K + lkq * 8;
        }

        bf16x8 a0[4], a1[4];
#pragma unroll
        for (int i = 0; i < 4; ++i) a0[i] = *(const bf16x8*)(ap[i]);
#pragma unroll
        for (int s = 0; s < K / 32; ++s) {
            bf16x8* cur = (s & 1) ? a1 : a0;
            bf16x8* nxt = (s & 1) ? a0 : a1;
            if (s + 1 < K / 32) {
#pragma unroll
                for (int i = 0; i < 4; ++i)
                    nxt[i] = *(const bf16x8*)(ap[i] + (s + 1) * 32);
            }
            bf16x8 bfr[4];
#pragma unroll
            for (int j = 0; j < 4; ++j)
                bfr[j] = *(const bf16x8*)(bbase + j * 16 * KP + s * 32);
#pragma unroll
            for (int i = 0; i < 4; ++i)
#pragma unroll
                for (int j = 0; j < 4; ++j)
                    acc[i][j] = __builtin_amdgcn_mfma_f32_16x16x32_bf16(
                        cur[i], bfr[j], acc[i][j], 0, 0, 0);
        }

#pragma unroll
        for (int j = 0; j < 4; ++j) {
            int colc = n0 + ((wc * 4 + j) << 4) + lrow;
            float bj = BIAS ? bias[colc] : 0.f;
#pragma unroll
            for (int i = 0; i < 4; ++i) {
                int rb = m0 + wr * 64 + i * 16 + (lkq << 2);
                f32x4 c = acc[i][j];
#pragma unroll
                for (int r = 0; r < 4; ++r) {
                    int rowc = rb + r;
                    if (rowc < Nrows) {
                        float v = c[r] + bj;
                        if (RELU) v = fmaxf(v, 0.f);
                        C[(size_t)rowc * Dout + colc] = f2bf(v);
                    }
                }
            }
        }
    }
}

// ----------------------------- launch --------------------------------------

extern "C" void kernel_launch(void* const* d_in, const int* in_sizes, int n_in,
                              void* d_out, int out_size, void* d_ws, size_t ws_size,
                              hipStream_t stream) {
    const float* x  = (const float*)d_in[0];
    const int*   ei = (const int*)d_in[1];
    const float* W0 = (const float*)d_in[4];
    const float* b0 = (const float*)d_in[5];
    const float* W1 = (const float*)d_in[6];
    const float* b1 = (const float*)d_in[7];
    const float* W2 = (const float*)d_in[8];
    const float* b2 = (const float*)d_in[9];

    const int N = in_sizes[0] / 128;
    const int E = in_sizes[1] / 2;
    const int* row = ei;       // sources
    const int* col = ei + E;   // destinations

    char* wp = (char*)d_ws;
    auto carve = [&](size_t bytes) {
        void* p = (void*)wp;
        wp += (bytes + 255) & ~(size_t)255;
        return p;
    };
    const int NB = (N + 2047) / 2048;
    int*   cnt    = (int*)carve((size_t)N * 4);
    int*   offs   = (int*)carve((size_t)(N + 1) * 4);
    unsigned short* rank = (unsigned short*)carve((size_t)E * 2);
    int*   esrc   = (int*)carve((size_t)E * 4);
    float* dinv   = (float*)carve((size_t)N * 4);
    int*   bsums  = (int*)carve((size_t)NB * 4);
    unsigned short* Wt0 = (unsigned short*)carve((size_t)256 * 128 * 2);
    unsigned short* Wt1 = (unsigned short*)carve((size_t)256 * 256 * 2);
    unsigned short* Wt2 = (unsigned short*)carve((size_t)128 * 256 * 2);
    unsigned short* regX = (unsigned short*)carve((size_t)N * 256 * 2);
    unsigned short* xb    = regX;                    // N*128 bf16
    unsigned short* agg0b = regX + (size_t)N * 128;  // N*128 bf16
    unsigned short* h2b   = regX;                    // N*256 (agg0b dead by then)
    unsigned short* h1b = (unsigned short*)carve((size_t)N * 256 * 2);
    unsigned short* hwb = h1b;                       // N*128 (h1b dead by then)
    unsigned short* agg1b = (unsigned short*)carve((size_t)N * 256 * 2);

    // --- CSR build ---
    hipMemsetAsync(cnt, 0, (size_t)N * 4, stream);
    count_edges<<<(E / 4 + 255) / 256, 256, 0, stream>>>(col, E, cnt, rank);
    scan_reduce<<<NB, 256, 0, stream>>>(cnt, N, bsums);
    scan_finish<<<NB, 256, 0, stream>>>(cnt, N, bsums, NB, offs, dinv);
    fill_csr<<<(E / 4 + 255) / 256, 256, 0, stream>>>(row, col, rank, E, offs, esrc);

    // --- fused converts ---
    {
        int n4 = N * 128 / 4;
        int tot = n4 + 32768 + 65536 + 32768;
        conv_fused<<<(tot + 255) / 256, 256, 0, stream>>>(
            (const float4*)x, (uint2*)xb, n4, W0, W1, W2, Wt0, Wt1, Wt2);
    }

    const int aggBlocks = (N + 3) / 4;  // 1 node/wave

    // GEMM grids: x = Dout/128 col-panels; y = persistent M-stride.
    // gemm0: K=128 -> 34KB LDS (4 blk/CU): y=391 gives 782 blocks, 2 tiles each.
    // gemm1: K=256 -> 68KB LDS (2 blk/CU): y=256 -> 512 resident, 3-4 tiles.
    // gemm2: K=256, Dout=128: y=391 -> 391 blocks, 2 tiles each, single round.

    // L0: agg0 = Â xb ; h1 = relu(agg0 @ W0 + b0)
    aggregate_g<128, true, false><<<aggBlocks, 256, 0, stream>>>(
        (const unsigned*)xb, dinv, offs, esrc, nullptr, agg0b, N);
    gemm_blds<128, true, true><<<dim3(2, 391), 256, 0, stream>>>(
        agg0b, Wt0, b0, h1b, N, 256);
    // L1: agg1 = Â h1 ; h2 = relu(agg1 @ W1 + b1)
    aggregate_g<256, true, false><<<aggBlocks, 256, 0, stream>>>(
        (const unsigned*)h1b, dinv, offs, esrc, nullptr, agg1b, N);
    gemm_blds<256, true, true><<<dim3(2, 256), 256, 0, stream>>>(
        agg1b, Wt1, b1, h2b, N, 256);
    // L2: hw = h2 @ W2 ; out = Â hw + b2 (fp32)
    gemm_blds<256, false, false><<<dim3(1, 391), 256, 0, stream>>>(
        h2b, Wt2, nullptr, hwb, N, 128);
    aggregate_g<128, false, true><<<aggBlocks, 256, 0, stream>>>(
        (const unsigned*)hwb, dinv, offs, esrc, b2, d_out, N);
}